// Round 1
// 1156.607 us; speedup vs baseline: 2.0419x; 2.0419x over previous
//
#include <hip/hip_runtime.h>
#include <cmath>

// Problem constants
#define NIMG 5
#define CCH  256
#define HHH  128
#define WWW  128
#define HW   16384            // 128*128
#define NPIX 81920            // 5*16384
#define SF_ELEMS 20971520     // 5*256*16384
#define LOSS_OFF 20971520
#define RATE_OFF 20971521
#define MASK_OFF 20971522

typedef __attribute__((ext_vector_type(4))) float f32x4;
typedef __attribute__((ext_vector_type(8))) __bf16 bf16x8;
typedef __attribute__((ext_vector_type(8))) unsigned short u16x8;

__device__ __forceinline__ unsigned short f32_to_bf16(float f) {
  unsigned int u = __float_as_uint(f);
  u += 0x7FFFu + ((u >> 16) & 1u);   // round-to-nearest-even
  return (unsigned short)(u >> 16);
}

__device__ __forceinline__ double sigmoid_d(double x) { return 1.0 / (1.0 + exp(-x)); }

__device__ __forceinline__ float softplus_f(float x) {
  if (x > 20.f) return x;
  if (x < -20.f) return expf(x);
  return log1pf(expf(x));
}

// g2 kernel value, computed as numpy does (f64 then cast f32), promoted back to double
__device__ __forceinline__ double g2w(int ky, int kx) {
  int d2 = (ky - 1) * (ky - 1) + (kx - 1) * (kx - 1);
  double g = 0.15915494309189535 * exp(-0.5 * (double)d2);
  return (double)(float)g;
}

// async global->LDS, 16 bytes per lane (dest = wave-uniform base + lane*16)
__device__ __forceinline__ void gload16(const unsigned short* g, void* l) {
  __builtin_amdgcn_global_load_lds((const __attribute__((address_space(1))) void*)g,
                                   (__attribute__((address_space(3))) void*)l, 16, 0, 0);
}

// ---------------- K0: zero accumulators ----------------
__global__ void k0_init(double* S1, double* S2, unsigned long long* cnt) {
  if (threadIdx.x == 0 && blockIdx.x == 0) { *S1 = 0.0; *S2 = 0.0; *cnt = 0ull; }
}

// ---------------- K1: per-(n,c) mean & max over HW ----------------
__global__ void k1_rednc(const float* __restrict__ feat, double* __restrict__ avg_d,
                         double* __restrict__ mx_d) {
  int nc = blockIdx.x;            // 0..1279
  int t = threadIdx.x;            // 256 threads
  const float* p = feat + (size_t)nc * HW;
  double s = 0.0;
  float m = -3.4e38f;
  for (int i = t; i < HW; i += 256) { float v = p[i]; s += (double)v; m = fmaxf(m, v); }
  __shared__ double sd[256];
  __shared__ float sm[256];
  sd[t] = s; sm[t] = m;
  __syncthreads();
  for (int o = 128; o > 0; o >>= 1) {
    if (t < o) { sd[t] += sd[t + o]; sm[t] = fmaxf(sm[t], sm[t + o]); }
    __syncthreads();
  }
  if (t == 0) { avg_d[nc] = sd[0] / 16384.0; mx_d[nc] = (double)sm[0]; }
}

// ---------------- K2: per-(n,p) channel mean & max ----------------
__global__ void k2_rednp(const float* __restrict__ feat, double* __restrict__ chmean,
                         double* __restrict__ chmax) {
  int gid = blockIdx.x * 256 + threadIdx.x;   // 0..81919
  int n = gid >> 14, p = gid & (HW - 1);
  const float* base = feat + (size_t)n * CCH * HW + p;
  double s = 0.0;
  float m = -3.4e38f;
  for (int c = 0; c < CCH; ++c) { float v = base[(size_t)c * HW]; s += (double)v; m = fmaxf(m, v); }
  chmean[gid] = s / 256.0;
  chmax[gid] = (double)m;
}

// ---------------- K3: channel-attention MLP + fusion + 1d conv (one block) -------
__global__ void k3_chan(const double* __restrict__ avg_d, const double* __restrict__ mx_d,
                        const float* __restrict__ w1, const float* __restrict__ w2,
                        const float* __restrict__ fus, double* __restrict__ chcoef_d) {
  __shared__ double hid_a[NIMG][16], hid_m[NIMG][16];
  __shared__ double att[NIMG][CCH];
  __shared__ double sig[4][CCH];
  int t = threadIdx.x;   // 256 threads, t = channel
  if (t < NIMG * 16) {
    int n = t / 16, j = t % 16;
    double sa = 0.0, sx = 0.0;
    for (int c = 0; c < CCH; ++c) {
      double w = (double)w1[j * CCH + c];
      sa += avg_d[n * CCH + c] * w;
      sx += mx_d[n * CCH + c] * w;
    }
    hid_a[n][j] = sa > 0.0 ? sa : 0.0;
    hid_m[n][j] = sx > 0.0 ? sx : 0.0;
  }
  __syncthreads();
  for (int n = 0; n < NIMG; ++n) {
    double oa = 0.0, om = 0.0;
    for (int j = 0; j < 16; ++j) {
      double w = (double)w2[t * 16 + j];
      oa += hid_a[n][j] * w;
      om += hid_m[n][j] * w;
    }
    att[n][t] = sigmoid_d(oa + om);
  }
  __syncthreads();
  for (int m = 0; m < 4; ++m) {
    double s = 0.0;
    for (int k = 0; k < CCH; ++k) {
      s += (1.0 - att[0][k]) * (double)fus[t * 512 + k]
         + att[m + 1][k] * (double)fus[t * 512 + 256 + k];
    }
    sig[m][t] = sigmoid_d(s);
  }
  __syncthreads();
  // g1, computed as numpy float32 does
  float a32 = (float)exp(-0.5);
  float s32 = (a32 + 1.0f) + a32;
  double ge = (double)(a32 / s32);
  double gc = (double)(1.0f / s32);
  for (int m = 0; m < 4; ++m) {
    double L = (t > 0) ? sig[m][t - 1] : 0.0;
    double R = (t < 255) ? sig[m][t + 1] : 0.0;
    chcoef_d[m * CCH + t] = ge * L + gc * sig[m][t] + ge * R;
  }
}

// ---------------- K4: spatial attention conv + act (gaussian of sigmoid(mean)) ----
__global__ void k4_spatial(const double* __restrict__ chmean, const double* __restrict__ chmax,
                           const float* __restrict__ spw, double* __restrict__ spatt,
                           double* __restrict__ actb) {
  int gid = blockIdx.x * 256 + threadIdx.x;   // 0..81919
  int n = gid >> 14, p = gid & (HW - 1);
  int y = p >> 7, x = p & 127;
  const double* cm = chmean + (size_t)n * HW;
  const double* cx = chmax + (size_t)n * HW;
  double s = 0.0, a = 0.0;
  for (int ky = 0; ky < 3; ++ky) {
    int yy = y + ky - 1;
    if ((unsigned)yy >= 128u) continue;
    for (int kx = 0; kx < 3; ++kx) {
      int xx = x + kx - 1;
      if ((unsigned)xx >= 128u) continue;
      int q = (yy << 7) + xx;
      s += (double)spw[ky * 3 + kx] * cm[q] + (double)spw[9 + ky * 3 + kx] * cx[q];
      a += g2w(ky, kx) * sigmoid_d(cm[q]);
    }
  }
  spatt[gid] = sigmoid_d(s);
  actb[gid] = a;
}

// ---------------- K5a: spatial fusion sigmoid ----------------
__global__ void k5a_spsig(const double* __restrict__ spatt, const float* __restrict__ fus2,
                          double* __restrict__ spsig) {
  int gid = blockIdx.x * 256 + threadIdx.x;   // 0..65535
  int m = gid >> 14, p = gid & (HW - 1);
  double wa = (double)fus2[0], wb = (double)fus2[1];
  double ego = 1.0 - spatt[p];                // n = 0
  spsig[gid] = sigmoid_d(wa * ego + wb * spatt[(size_t)(m + 1) * HW + p]);
}

// ---------------- K5b: gaussian conv of sp_sig, times act[m+1] ----------------
__global__ void k5b_spcoef(const double* __restrict__ spsig, const double* __restrict__ actb,
                           double* __restrict__ spact) {
  int gid = blockIdx.x * 256 + threadIdx.x;   // 0..65535
  int m = gid >> 14, p = gid & (HW - 1);
  int y = p >> 7, x = p & 127;
  const double* sp = spsig + (size_t)m * HW;
  double s = 0.0;
  for (int ky = 0; ky < 3; ++ky) {
    int yy = y + ky - 1;
    if ((unsigned)yy >= 128u) continue;
    for (int kx = 0; kx < 3; ++kx) {
      int xx = x + kx - 1;
      if ((unsigned)xx >= 128u) continue;
      s += g2w(ky, kx) * sp[(yy << 7) + xx];
    }
  }
  spact[gid] = s * actb[(size_t)(m + 1) * HW + p];
}

// ---------------- K6: mask + sparse_feature + sparse_mask + count ----------------
__global__ void k6_mask(const float* __restrict__ feat, const double* __restrict__ chcoef,
                        const double* __restrict__ spact, float* __restrict__ out_sf,
                        float* __restrict__ out_mask, unsigned long long* __restrict__ cnt) {
  const int nth = gridDim.x * blockDim.x;
  int cl = 0;
  for (int g4 = blockIdx.x * blockDim.x + threadIdx.x; g4 < SF_ELEMS / 4; g4 += nth) {
    size_t e = (size_t)g4 * 4;
    int nc = (int)(e >> 14);
    int p = (int)(e & (HW - 1));
    int n = nc >> 8, c = nc & 255;
    f32x4 v = __builtin_nontemporal_load((const f32x4*)&feat[e]);
    f32x4 mk;
    if (n == 0) {
      mk = (f32x4){1.f, 1.f, 1.f, 1.f};
    } else {
      double cc = chcoef[(n - 1) * CCH + c];
      const double* sp = &spact[(size_t)(n - 1) * HW + p];
#pragma unroll
      for (int l = 0; l < 4; ++l) {
        float m = (cc * sp[l] > 0.01) ? 1.f : 0.f;
        mk[l] = m;
        cl += (m != 0.f);
      }
    }
    f32x4 o;
#pragma unroll
    for (int l = 0; l < 4; ++l) o[l] = v[l] * mk[l];
    __builtin_nontemporal_store(o, (f32x4*)&out_sf[e]);
    __builtin_nontemporal_store(mk, (f32x4*)&out_mask[e]);
  }
#pragma unroll
  for (int off = 32; off > 0; off >>= 1) cl += __shfl_down(cl, off);
  if ((threadIdx.x & 63) == 0 && cl > 0) atomicAdd(cnt, (unsigned long long)cl);
}

// ---------------- K7: weight conversion f32 -> bf16 ----------------
__global__ void k7_wconv(const float* __restrict__ w1, const float* __restrict__ w2,
                         unsigned short* __restrict__ W1b, unsigned short* __restrict__ W2b) {
  int gid = blockIdx.x * 256 + threadIdx.x;   // 0..1048575
  if (gid < 524288) W1b[gid] = f32_to_bf16(w1[gid]);
  W2b[gid] = f32_to_bf16(w2[gid]);
}

// ---------------- K6b: transpose feat & sf to K-contiguous bf16 ------------------
// featT/sfT layout: [n][p][c] (row-stride 256 shorts). 64x64 tiles via LDS.
__global__ void k6b_transpose(const float* __restrict__ feat, const float* __restrict__ sf,
                              unsigned short* __restrict__ featT, unsigned short* __restrict__ sfT) {
  __shared__ unsigned short tf[64][65];
  __shared__ unsigned short tsb[64][65];
  const int bid = blockIdx.x;
  const int n  = bid >> 10;            // 0..4
  const int r  = bid & 1023;
  const int ct = r >> 8;               // 0..3  (64-channel tile)
  const int pt = r & 255;              // 0..255 (64-pixel tile)
  const int c0 = ct << 6, p0 = pt << 6;
  const int t = threadIdx.x;
  {
    const int cy = t >> 2, px4 = (t & 3) << 4;
    const float* fp = feat + ((size_t)n * 256 + c0 + cy) * HW + p0 + px4;
    const float* sp = sf   + ((size_t)n * 256 + c0 + cy) * HW + p0 + px4;
#pragma unroll
    for (int i = 0; i < 4; ++i) {
      f32x4 v = *(const f32x4*)(fp + i * 4);
      f32x4 u = *(const f32x4*)(sp + i * 4);
#pragma unroll
      for (int j = 0; j < 4; ++j) {
        tf[cy][px4 + i * 4 + j]  = f32_to_bf16(v[j]);
        tsb[cy][px4 + i * 4 + j] = f32_to_bf16(u[j]);
      }
    }
  }
  __syncthreads();
  {
    const int py = t >> 2, cx = (t & 3) << 4;
    u16x8 o0, o1, q0, q1;
#pragma unroll
    for (int k = 0; k < 8; ++k) { o0[k] = tf[cx + k][py];     q0[k] = tsb[cx + k][py]; }
#pragma unroll
    for (int k = 0; k < 8; ++k) { o1[k] = tf[cx + 8 + k][py]; q1[k] = tsb[cx + 8 + k][py]; }
    size_t ob = ((size_t)n * HW + p0 + py) * 256 + c0 + cx;
    *(u16x8*)&featT[ob]     = o0;
    *(u16x8*)&featT[ob + 8] = o1;
    *(u16x8*)&sfT[ob]       = q0;
    *(u16x8*)&sfT[ob + 8]   = q1;
  }
}

// ---------------- KT0: zero the T accumulator ----------------
__global__ void kT0_zero(float* __restrict__ T) {
  int g = blockIdx.x * 256 + threadIdx.x;
  for (int i = g; i < 163840; i += gridDim.x * 256) T[i] = 0.f;
}

// ---------------- K8 GEMM engine: 128x128 tile, BK=32, dbuf global_load_lds ------
// L1=true : A = xcat (featT/sfT split at K=256), B = W1b (ldb 512), NT=16,
//           epilogue relu(+b1) -> H1 bf16 [40960][1024].
// L1=false: A = H1 chunk, B = W2b (ldb 1024), NT=32,
//           epilogue relu(+b2)*w3, row-sum -> atomicAdd T[global row].
template<int NT, bool L1>
__global__ __launch_bounds__(256, 2) void k8_gemm(
    const unsigned short* __restrict__ A0,   // featT | H1
    const unsigned short* __restrict__ A1,   // sfT   | unused
    const unsigned short* __restrict__ Wb,   // W1b   | W2b
    const float* __restrict__ bias,          // b1    | b2
    const float* __restrict__ w3,            // -     | st_w3
    unsigned short* __restrict__ H1,         // out   | -
    float* __restrict__ Tout,                // -     | out
    int m_base) {
  __shared__ unsigned short lds[16384];      // A dbuf [0,8192), B dbuf [8192,16384)

  // bijective XCD swizzle (2560 % 8 == 0): each XCD gets contiguous mtile groups
  const int bid0 = blockIdx.x;
  const int sb = (bid0 & 7) * 320 + (bid0 >> 3);
  const int mt = sb >> 3, nt = sb & 7;

  const int t = threadIdx.x, l = t & 63, w = t >> 6;   // 4 waves, 2x2 wave grid
  const int wr = w >> 1, wc = w & 1;
  const int n16 = l & 15, quad = l >> 4;
  constexpr int ldb = L1 ? 512 : 1024;

  // resolve A base pointers
  const unsigned short* base_feat = nullptr;
  const unsigned short* base_sf = nullptr;
  const unsigned short* base_a = nullptr;
  if constexpr (L1) {
    const int g0 = m_base + mt * 128;       // global row of tile
    const int branch = (g0 >= NPIX) ? 1 : 0;
    const int rl = g0 - branch * NPIX;
    const int img = rl >> 14;
    const int p0 = rl & (HW - 1);
    const int img_f = branch ? (img + 1 == NIMG ? 0 : img + 1) : img;
    base_feat = A0 + ((size_t)img_f * HW + p0) * 256;
    base_sf   = A1 + ((size_t)img   * HW + p0) * 256;
  } else {
    base_a = A0 + (size_t)(mt * 128) * 1024;
  }
  const unsigned short* base_b = Wb + (size_t)(nt * 128) * ldb;

  const int r0 = l >> 2;              // staging: lane row within 16-row segment
  const int kk = (l & 3) * 8;         // staging: lane k offset (shorts)

  auto stage = [&](int buf, int ts) {
    const unsigned short* Ap;
    size_t as;
    if constexpr (L1) {
      if (ts < 8) { Ap = base_feat + ts * 32; } else { Ap = base_sf + (ts - 8) * 32; }
      as = 256;
    } else {
      Ap = base_a + ts * 32;
      as = 1024;
    }
    const unsigned short* Bp = base_b + ts * 32;
#pragma unroll
    for (int j = 0; j < 2; ++j) {
      const int s = w * 2 + j;        // 16-row segment, wave-uniform
      gload16(Ap + (size_t)(s * 16 + r0) * as + kk, (void*)&lds[buf * 4096 + s * 512]);
      gload16(Bp + (size_t)(s * 16 + r0) * (size_t)ldb + kk, (void*)&lds[8192 + buf * 4096 + s * 512]);
    }
  };

  f32x4 acc[4][4];
  {
    f32x4 z = {0.f, 0.f, 0.f, 0.f};
#pragma unroll
    for (int g = 0; g < 4; ++g)
#pragma unroll
      for (int j = 0; j < 4; ++j) acc[g][j] = z;
  }

  stage(0, 0);
  for (int ts = 0; ts < NT; ++ts) {
    const int cur = ts & 1;
    if (ts + 1 < NT) {
      stage(cur ^ 1, ts + 1);                       // prefetch next tile (other buffer)
      asm volatile("s_waitcnt vmcnt(4)" ::: "memory");   // own cur-tile loads done, next in flight
    } else {
      asm volatile("s_waitcnt vmcnt(0)" ::: "memory");
    }
    asm volatile("s_barrier" ::: "memory");          // cur tile fully staged (all waves)

    const int abase = cur * 4096 + (wr * 64) * 32;
    const int bbase = 8192 + cur * 4096 + (wc * 64) * 32;
    bf16x8 af[4], bg[4];
#pragma unroll
    for (int g = 0; g < 4; ++g) af[g] = *(const bf16x8*)&lds[abase + (g * 16 + n16) * 32 + quad * 8];
#pragma unroll
    for (int j = 0; j < 4; ++j) bg[j] = *(const bf16x8*)&lds[bbase + (j * 16 + n16) * 32 + quad * 8];
#pragma unroll
    for (int g = 0; g < 4; ++g)
#pragma unroll
      for (int j = 0; j < 4; ++j)
        acc[g][j] = __builtin_amdgcn_mfma_f32_16x16x32_bf16(af[g], bg[j], acc[g][j], 0, 0, 0);

    asm volatile("s_waitcnt lgkmcnt(0)" ::: "memory");   // ds_reads retired -> safe to overwrite
    asm volatile("s_barrier" ::: "memory");
  }

  const int colb = nt * 128 + wc * 64;
  if constexpr (L1) {
    const size_t mloc0 = (size_t)(mt * 128 + wr * 64);
#pragma unroll
    for (int j = 0; j < 4; ++j) {
      const int col = colb + j * 16 + n16;
      const float bv = bias[col];
#pragma unroll
      for (int g = 0; g < 4; ++g) {
#pragma unroll
        for (int rr = 0; rr < 4; ++rr) {
          float v = acc[g][j][rr] + bv;
          v = v > 0.f ? v : 0.f;
          H1[(mloc0 + g * 16 + quad * 4 + rr) * 1024 + col] = f32_to_bf16(v);
        }
      }
    }
  } else {
    float rs[4][4];
#pragma unroll
    for (int g = 0; g < 4; ++g)
#pragma unroll
      for (int rr = 0; rr < 4; ++rr) rs[g][rr] = 0.f;
#pragma unroll
    for (int j = 0; j < 4; ++j) {
      const int col = colb + j * 16 + n16;
      const float bv = bias[col];
      const float wv = w3[col];
#pragma unroll
      for (int g = 0; g < 4; ++g) {
#pragma unroll
        for (int rr = 0; rr < 4; ++rr) {
          float v = acc[g][j][rr] + bv;
          v = v > 0.f ? v : 0.f;
          rs[g][rr] += v * wv;
        }
      }
    }
    // reduce across the 16 col-lanes (lane bits 0..3)
#pragma unroll
    for (int off = 1; off < 16; off <<= 1) {
#pragma unroll
      for (int g = 0; g < 4; ++g)
#pragma unroll
        for (int rr = 0; rr < 4; ++rr) rs[g][rr] += __shfl_xor(rs[g][rr], off);
    }
    if (n16 == 0) {
      const int row0 = m_base + mt * 128 + wr * 64;
#pragma unroll
      for (int g = 0; g < 4; ++g)
#pragma unroll
        for (int rr = 0; rr < 4; ++rr)
          atomicAdd(&Tout[row0 + g * 16 + quad * 4 + rr], rs[g][rr]);
    }
  }
}

// ---------------- K8c: softplus reduce of T into S1/S2 ----------------
__global__ void k8c_red(const float* __restrict__ T, const float* __restrict__ b3,
                        double* __restrict__ S1, double* __restrict__ S2) {
  const int gid = blockIdx.x * 256 + threadIdx.x;
  const int stride = gridDim.x * 256;
  const float bv = b3[0];
  double s1 = 0.0, s2 = 0.0;
  for (int r = gid; r < 163840; r += stride) {
    float Tv = T[r] + bv;
    if (r < NPIX) s1 += (double)softplus_f(-Tv);
    else          s2 += (double)softplus_f(Tv);
  }
#pragma unroll
  for (int off = 32; off > 0; off >>= 1) {
    s1 += __shfl_down(s1, off);
    s2 += __shfl_down(s2, off);
  }
  __shared__ double l1[4], l2[4];
  const int wv = threadIdx.x >> 6;
  if ((threadIdx.x & 63) == 0) { l1[wv] = s1; l2[wv] = s2; }
  __syncthreads();
  if (threadIdx.x == 0) {
    atomicAdd(S1, l1[0] + l1[1] + l1[2] + l1[3]);
    atomicAdd(S2, l2[0] + l2[1] + l2[2] + l2[3]);
  }
}

// ---------------- old fused K8 (fallback when workspace is small) ----------------
__device__ __forceinline__ int xidx(int row, int c) {    // xcat: row-stride 512 shorts
  return row * 512 + ((((c >> 3) ^ (row & 7)) << 3) | (c & 7));
}
__device__ __forceinline__ int hidx(int row, int oc) {   // h1 chunk: row-stride 256 shorts
  return 32768 + row * 256 + ((((oc >> 3) ^ (row & 7)) << 3) | (oc & 7));
}

__global__ __launch_bounds__(1024, 4) void k8_stat(
    const float* __restrict__ feat, const float* __restrict__ sf,
    const unsigned short* __restrict__ W1b, const unsigned short* __restrict__ W2b,
    const float* __restrict__ b1, const float* __restrict__ b2,
    const float* __restrict__ w3, const float* __restrict__ b3,
    double* __restrict__ S1, double* __restrict__ S2) {
  __shared__ unsigned short lds[49280];          // 98560 B
  float* t_acc = (float*)&lds[49152];            // 64 floats

  const int bid = blockIdx.x;
  const int n = bid >> 9;                        // 512 tiles of 32 px per image
  const int p0 = (bid & 511) << 5;
  const int n1 = (n + 1 == NIMG) ? 0 : n + 1;

  const int t = threadIdx.x;                     // 1024 threads = 16 waves
  const int lane = t & 63;
  const int w = t >> 6;                          // wave 0..15
  const int n16 = lane & 15;
  const int quad = lane >> 4;

  {
    const int c = t & 511;
    const int half = t >> 9;
    if (t < 64) t_acc[t] = 0.f;
#pragma unroll
    for (int rb = 0; rb < 2; ++rb) {
      const float* s = (c < 256)
          ? feat + ((size_t)(rb ? n1 : n) * CCH + c) * HW + p0
          : sf + ((size_t)n * CCH + (c - 256)) * HW + p0;
      const f32x4* s4 = (const f32x4*)(s + half * 16);
#pragma unroll
      for (int i = 0; i < 4; ++i) {
        f32x4 v = __builtin_nontemporal_load(s4 + i);
        const int prow = rb * 32 + half * 16 + i * 4;
#pragma unroll
        for (int l = 0; l < 4; ++l) lds[xidx(prow + l, c)] = f32_to_bf16(v[l]);
      }
    }
  }
  __syncthreads();

  f32x4 acc2[4][4];
  {
    f32x4 z = {0.f, 0.f, 0.f, 0.f};
#pragma unroll
    for (int g = 0; g < 4; ++g)
#pragma unroll
      for (int jt = 0; jt < 4; ++jt) acc2[g][jt] = z;
  }

  for (int nc = 0; nc < 4; ++nc) {
    f32x4 acc1[4];
    {
      f32x4 z = {0.f, 0.f, 0.f, 0.f};
#pragma unroll
      for (int g = 0; g < 4; ++g) acc1[g] = z;
    }
    const int o = nc * 256 + w * 16 + n16;
    const unsigned short* Wrow = W1b + (size_t)o * 512;
    bf16x8 bnxt = *(const bf16x8*)&Wrow[quad * 8];
    for (int ks = 0; ks < 16; ++ks) {
      bf16x8 b = bnxt;
      if (ks < 15) bnxt = *(const bf16x8*)&Wrow[(ks + 1) * 32 + quad * 8];
      const int cb = ks * 32 + quad * 8;
#pragma unroll
      for (int g = 0; g < 4; ++g) {
        bf16x8 a = *(const bf16x8*)&lds[xidx(g * 16 + n16, cb)];
        acc1[g] = __builtin_amdgcn_mfma_f32_16x16x32_bf16(a, b, acc1[g], 0, 0, 0);
      }
    }
    __syncthreads();

    {
      const float bv = b1[o];
      const int ol = w * 16 + n16;
#pragma unroll
      for (int g = 0; g < 4; ++g) {
#pragma unroll
        for (int r = 0; r < 4; ++r) {
          const int row = g * 16 + quad * 4 + r;
          float v = acc1[g][r] + bv;
          v = v > 0.f ? v : 0.f;
          lds[hidx(row, ol)] = f32_to_bf16(v);
        }
      }
    }
    __syncthreads();

    for (int ksl = 0; ksl < 8; ++ksl) {
      const int ocb = ksl * 32 + quad * 8;
      bf16x8 a[4];
#pragma unroll
      for (int g = 0; g < 4; ++g) a[g] = *(const bf16x8*)&lds[hidx(g * 16 + n16, ocb)];
#pragma unroll
      for (int jt = 0; jt < 4; ++jt) {
        const int o2 = w * 64 + jt * 16 + n16;
        bf16x8 b = *(const bf16x8*)&W2b[(size_t)o2 * 1024 + nc * 256 + ocb];
#pragma unroll
        for (int g = 0; g < 4; ++g)
          acc2[g][jt] = __builtin_amdgcn_mfma_f32_16x16x32_bf16(a[g], b, acc2[g][jt], 0, 0, 0);
      }
    }
  }

  float tp[4][4];
#pragma unroll
  for (int g = 0; g < 4; ++g)
#pragma unroll
    for (int r = 0; r < 4; ++r) tp[g][r] = 0.f;
#pragma unroll
  for (int jt = 0; jt < 4; ++jt) {
    const int o2 = w * 64 + jt * 16 + n16;
    const float bv = b2[o2];
    const float wv = w3[o2];
#pragma unroll
    for (int g = 0; g < 4; ++g) {
#pragma unroll
      for (int r = 0; r < 4; ++r) {
        float v = acc2[g][jt][r] + bv;
        v = v > 0.f ? v : 0.f;
        tp[g][r] += v * wv;
      }
    }
  }
#pragma unroll
  for (int off = 1; off < 16; off <<= 1) {
#pragma unroll
    for (int g = 0; g < 4; ++g)
#pragma unroll
      for (int r = 0; r < 4; ++r) tp[g][r] += __shfl_xor(tp[g][r], off);
  }
  if (n16 == 0) {
#pragma unroll
    for (int g = 0; g < 4; ++g)
#pragma unroll
      for (int r = 0; r < 4; ++r) atomicAdd(&t_acc[g * 16 + quad * 4 + r], tp[g][r]);
  }
  __syncthreads();

  if (t < 64) {
    const float T = t_acc[t] + b3[0];
    float v = (t < 32) ? softplus_f(-T) : softplus_f(T);
#pragma unroll
    for (int off = 16; off > 0; off >>= 1) v += __shfl_down(v, off);
    if (t == 0) atomicAdd(S1, (double)v);
    if (t == 32) atomicAdd(S2, (double)v);
  }
}

// ---------------- K9: finalize scalars ----------------
__global__ void k9_final(const double* __restrict__ S1, const double* __restrict__ S2,
                         const unsigned long long* __restrict__ cnt, float* __restrict__ out) {
  if (threadIdx.x == 0 && blockIdx.x == 0) {
    out[LOSS_OFF] = (float)(((*S1) + (*S2)) / 81920.0);
    out[RATE_OFF] = (float)((double)(*cnt) / 16777216.0);
  }
}

// new-path workspace layout (bytes)
#define WS_FEATT 8388608ull
#define WS_SFT   50331648ull
#define WS_H1    92274688ull
#define WS_T     176160768ull
#define WS_NEED  176816128ull

extern "C" void kernel_launch(void* const* d_in, const int* in_sizes, int n_in,
                              void* d_out, int out_size, void* d_ws, size_t ws_size,
                              hipStream_t stream) {
  const float* feat     = (const float*)d_in[0];
  const float* mlp_w1   = (const float*)d_in[1];
  const float* mlp_w2   = (const float*)d_in[2];
  const float* sp_req_w = (const float*)d_in[3];
  const float* ch_fus_w = (const float*)d_in[4];
  const float* sp_fus_w = (const float*)d_in[5];
  const float* st_w1    = (const float*)d_in[6];
  const float* st_b1    = (const float*)d_in[7];
  const float* st_w2    = (const float*)d_in[8];
  const float* st_b2    = (const float*)d_in[9];
  const float* st_w3    = (const float*)d_in[10];
  const float* st_b3    = (const float*)d_in[11];
  float* out = (float*)d_out;

  char* ws = (char*)d_ws;
  double* S1     = (double*)(ws + 0);
  double* S2     = (double*)(ws + 8);
  unsigned long long* cnt = (unsigned long long*)(ws + 16);
  double* avg_d  = (double*)(ws + 64);        // 1280
  double* mx_d   = (double*)(ws + 10304);     // 1280
  double* chmean = (double*)(ws + 20544);     // 81920
  double* chmax  = (double*)(ws + 675904);    // 81920
  double* spatt  = (double*)(ws + 1331264);   // 81920
  double* actb   = (double*)(ws + 1986624);   // 81920
  double* chcoef = (double*)(ws + 2652224);   // 1024
  double* spsig  = (double*)(ws + 2660416);   // 65536
  double* spact  = (double*)(ws + 3184704);   // 65536
  unsigned short* W1b = (unsigned short*)(ws + 3708992);  // 524288
  unsigned short* W2b = (unsigned short*)(ws + 4757568);  // 1048576

  k0_init<<<1, 64, 0, stream>>>(S1, S2, cnt);
  k1_rednc<<<1280, 256, 0, stream>>>(feat, avg_d, mx_d);
  k2_rednp<<<320, 256, 0, stream>>>(feat, chmean, chmax);
  k3_chan<<<1, 256, 0, stream>>>(avg_d, mx_d, mlp_w1, mlp_w2, ch_fus_w, chcoef);
  k4_spatial<<<320, 256, 0, stream>>>(chmean, chmax, sp_req_w, spatt, actb);
  k5a_spsig<<<256, 256, 0, stream>>>(spatt, sp_fus_w, spsig);
  k5b_spcoef<<<256, 256, 0, stream>>>(spsig, actb, spact);
  k7_wconv<<<4096, 256, 0, stream>>>(st_w1, st_w2, W1b, W2b);
  k6_mask<<<2048, 256, 0, stream>>>(feat, chcoef, spact, out, out + MASK_OFF, cnt);

  if (ws_size >= WS_NEED) {
    unsigned short* featT = (unsigned short*)(ws + WS_FEATT);
    unsigned short* sfT   = (unsigned short*)(ws + WS_SFT);
    unsigned short* H1    = (unsigned short*)(ws + WS_H1);
    float* Tb             = (float*)(ws + WS_T);
    k6b_transpose<<<5120, 256, 0, stream>>>(feat, out, featT, sfT);
    kT0_zero<<<160, 256, 0, stream>>>(Tb);
    for (int c = 0; c < 4; ++c) {
      k8_gemm<16, true><<<2560, 256, 0, stream>>>(featT, sfT, W1b, st_b1, nullptr, H1, nullptr, c * 40960);
      k8_gemm<32, false><<<2560, 256, 0, stream>>>(H1, nullptr, W2b, st_b2, st_w3, nullptr, Tb, c * 40960);
    }
    k8c_red<<<160, 256, 0, stream>>>(Tb, st_b3, S1, S2);
  } else {
    k8_stat<<<2560, 1024, 0, stream>>>(feat, out, W1b, W2b, st_b1, st_b2, st_w3, st_b3, S1, S2);
  }

  k9_final<<<1, 64, 0, stream>>>(S1, S2, cnt, out);
}